// Round 11
// baseline (208.140 us; speedup 1.0000x reference)
//
#include <hip/hip_runtime.h>
#include <hip/hip_bf16.h>

// ---------------------------------------------------------------------------
// AttentionHead B=4,S=2048,D=1024 — all-f16 pipeline, round 11.
// gemmO (new): 256x128, BK=32, 3-deep pipeline, 72 KiB LDS -> 2 blocks/CU.
//   r7-r10 lesson: every 1-block/CU schedule variant = ~950 TF; per-tile
//   exposed latency ~3300cyc has nothing to fill it. m97/m114: multi-block
//   co-residency is the proven latency-hiding mechanism at HIP level.
// softmax/converts/transposes unchanged.
// ws (MiB): XF@0(48) WT@48(6) PROJ@54(48) VT@102(16) SC@118(32,f16)
//           P@0(32,f16, alias XF). high-water 150 MiB.
// ---------------------------------------------------------------------------

typedef __attribute__((ext_vector_type(4))) float    f32x4;
typedef __attribute__((ext_vector_type(8))) _Float16 f16x8;
typedef __attribute__((ext_vector_type(4))) _Float16 f16x4;

constexpr size_t MiB = 1u << 20;
constexpr size_t MK  = (size_t)8192 * 1024;
constexpr size_t WSZ = (size_t)1024 * 1024;

__device__ __forceinline__ void gload_lds16(const void* g, void* l) {
  __builtin_amdgcn_global_load_lds(
      (const __attribute__((address_space(1))) unsigned int*)g,
      (__attribute__((address_space(3))) unsigned int*)l, 16, 0, 0);
}

#define MFMA16(a, b, c) __builtin_amdgcn_mfma_f32_16x16x32_f16(a, b, c, 0, 0, 0)

// XCD-chunked bijective block swizzle (requires total blocks % 8 == 0).
__device__ __forceinline__ void swz_block(int& bx, int& by, int& bz) {
  unsigned gx = gridDim.x, gy = gridDim.y;
  unsigned flat = blockIdx.x + gx * (blockIdx.y + gy * blockIdx.z);
  unsigned total = gx * gy * gridDim.z;
  unsigned cpx = total >> 3;
  unsigned s = (flat & 7) * cpx + (flat >> 3);
  bx = s % gx; s /= gx; by = s % gy; bz = s / gy;
}

// ---------------------------------------------------------------------------
__global__ __launch_bounds__(256) void convert_x(
    const float* __restrict__ x0, const float* __restrict__ x1,
    const float* __restrict__ x2, _Float16* __restrict__ XF)
{
  const int z = blockIdx.z;
  const float* x = z == 0 ? x0 : (z == 1 ? x1 : x2);
  size_t i = ((size_t)blockIdx.x * 256 + threadIdx.x) * 4;
  float4 v = *(const float4*)(x + i);
  f16x4 h = {(_Float16)v.x, (_Float16)v.y, (_Float16)v.z, (_Float16)v.w};
  *(f16x4*)(XF + (size_t)z * MK + i) = h;
}

// ---------------------------------------------------------------------------
__global__ __launch_bounds__(256) void transpose_conv_w(
    const float* __restrict__ w0, const float* __restrict__ w1,
    const float* __restrict__ w2, _Float16* __restrict__ WT)
{
  const int z = blockIdx.z;
  const float* W = z == 0 ? w0 : (z == 1 ? w1 : w2);
  _Float16* o = WT + (size_t)z * WSZ;
  __shared__ float tile[32][33];
  const int bx = blockIdx.x * 32;
  const int by = blockIdx.y * 32;
  const int tx = threadIdx.x & 31, ty = threadIdx.x >> 5;
  #pragma unroll
  for (int r = 0; r < 32; r += 8)
    tile[ty + r][tx] = W[(size_t)(by + ty + r) * 1024 + bx + tx];
  __syncthreads();
  #pragma unroll
  for (int r = 0; r < 32; r += 8)
    o[(size_t)(bx + ty + r) * 1024 + by + tx] = (_Float16)tile[tx][ty + r];
}

// ---------------------------------------------------------------------------
__global__ __launch_bounds__(256) void transpose_v(
    const _Float16* __restrict__ V, _Float16* __restrict__ Vt)
{
  const _Float16* v = V + (size_t)blockIdx.z * 2048 * 1024;
  _Float16* o = Vt + (size_t)blockIdx.z * 1024 * 2048;
  __shared__ _Float16 tile[32][33];
  const int bx = blockIdx.x * 32;   // e
  const int by = blockIdx.y * 32;   // s
  const int tx = threadIdx.x & 31, ty = threadIdx.x >> 5;
  #pragma unroll
  for (int r = 0; r < 32; r += 8)
    tile[ty + r][tx] = v[(size_t)(by + ty + r) * 1024 + bx + tx];
  __syncthreads();
  #pragma unroll
  for (int r = 0; r < 32; r += 8)
    o[(size_t)(bx + ty + r) * 2048 + by + tx] = tile[tx][ty + r];
}

// ---------------------------------------------------------------------------
// gemmO: 256(M)x128(N), BK=32, 512 thr = 8 waves (4M x 2N, wave 64x64).
// 3-deep pipeline, 3 x 24 KiB LDS buffers (A 16K @0, B 8K @16384 per buf)
// -> 72 KiB total -> 2 blocks/CU co-resident (the latency-hiding mechanism).
// Stage tile t+2 during t (3 gloads); boundary vmcnt(3) steady, 0 tail.
// Swizzle (64B rows, 4 chunks): phys_chunk = logical ^ (row&3), applied on
// the global source and on ds_read addrs (conflict-free; even rows banks
// 0-15, odd rows 16-31, 4 distinct chunks each).
// MODE 0: f32*scale ; 1: f16 ; 2: f16*scale.
template <int MODE>
__global__ __launch_bounds__(512, 4) void gemmO(
    const _Float16* __restrict__ At, size_t sA,
    const _Float16* __restrict__ Bt, size_t sB,
    void* __restrict__ Cv, size_t sCz,
    int N, int K, float scale)
{
  extern __shared__ char lds[];
  int bx, by, bz;
  swz_block(bx, by, bz);
  const _Float16* A = At + (size_t)bz * sA;
  const _Float16* B = Bt + (size_t)bz * sB;

  const int gm0 = by * 256, gn0 = bx * 128;
  const int tid = threadIdx.x;
  const int lane = tid & 63, wave = tid >> 6;
  const int wm = (wave >> 1) * 64;    // 4 M groups of 64
  const int wn = (wave & 1) * 64;     // 2 N groups of 64
  const int fr = lane & 15, fq = lane >> 4;
  const int nkt = K >> 5;

  // staging: thread t -> row t>>2 (A: +128 second gload), chunk (t&3)^(row&3)
  const int clog = ((tid & 3) ^ ((tid >> 2) & 3)) * 8;   // element offset
  const _Float16* srcA = A + (size_t)(gm0 + (tid >> 2)) * K + clog;
  const _Float16* srcB = B + (size_t)(gn0 + (tid >> 2)) * K + clog;
  char* const dst0 = lds + tid * 16;

  auto STG = [&](int tile) {
    const int off = tile * 32;
    char* d = dst0 + (tile % 3) * 24576;
    gload_lds16(srcA + off,                  d);
    gload_lds16(srcA + off + (size_t)128 * K, d + 8192);
    gload_lds16(srcB + off,                  d + 16384);
  };

  // fragment reads (swizzled): row stride 64B; pc = (fq ^ (fr&3))*16
  const int pc  = (fq ^ (fr & 3)) * 16;
  const int arb = (wm + fr) * 64 + pc;
  const int brb = 16384 + (wn + fr) * 64 + pc;

  f32x4 acc[4][4] = {};
  f16x8 af[4], bfr[4];

  // prologue: stage tiles 0,1 (6 loads); wait tile 0 (vmcnt 3)
  STG(0);
  if (nkt > 1) {
    STG(1);
    asm volatile("s_waitcnt vmcnt(3)" ::: "memory");
  } else {
    asm volatile("s_waitcnt vmcnt(0)" ::: "memory");
  }
  __builtin_amdgcn_s_barrier();
  __builtin_amdgcn_sched_barrier(0);

  for (int t = 0; t < nkt; ++t) {
    const char* buf = lds + (t % 3) * 24576;
    const bool st2 = (t + 2) < nkt;

    if (st2) STG(t + 2);   // buffer (t+2)%3 freed by iter t-1's barrier

    #pragma unroll
    for (int mi = 0; mi < 4; ++mi)
      af[mi] = *(const f16x8*)(buf + arb + mi * 1024);
    #pragma unroll
    for (int ni = 0; ni < 4; ++ni)
      bfr[ni] = *(const f16x8*)(buf + brb + ni * 1024);

    __builtin_amdgcn_s_setprio(1);
    #pragma unroll
    for (int mi = 0; mi < 4; ++mi)
      #pragma unroll
      for (int ni = 0; ni < 4; ++ni)
        acc[mi][ni] = MFMA16(af[mi], bfr[ni], acc[mi][ni]);
    __builtin_amdgcn_s_setprio(0);

    // boundary: tile t+1 must have landed; t+2's 3 loads may stay in flight
    if (st2)               asm volatile("s_waitcnt vmcnt(3)" ::: "memory");
    else if (t + 1 < nkt)  asm volatile("s_waitcnt vmcnt(0)" ::: "memory");
    __builtin_amdgcn_s_barrier();
    __builtin_amdgcn_sched_barrier(0);
  }

  // epilogue: C/D layout col=fr, row=fq*4+r
  const int erow = gm0 + wm + fq * 4;
  const int ecol = gn0 + wn + fr;
  #pragma unroll
  for (int m = 0; m < 4; ++m)
    #pragma unroll
    for (int n = 0; n < 4; ++n) {
      size_t base = (size_t)(erow + m * 16) * N + (ecol + n * 16);
      #pragma unroll
      for (int r = 0; r < 4; ++r) {
        float v = acc[m][n][r];
        if constexpr (MODE == 0)
          ((float*)Cv + (size_t)bz * sCz)[base + (size_t)r * N] = v * scale;
        else if constexpr (MODE == 1)
          ((_Float16*)Cv + (size_t)bz * sCz)[base + (size_t)r * N] = (_Float16)v;
        else
          ((_Float16*)Cv + (size_t)bz * sCz)[base + (size_t)r * N] =
              (_Float16)(v * scale);
      }
    }
}

// ---------------------------------------------------------------------------
// Wave-per-row softmax: scores [8192 rows][2048] f16 -> P f16. 4 rows/block.
__global__ __launch_bounds__(256) void softmax_rows(
    const _Float16* __restrict__ S, _Float16* __restrict__ P)
{
  const int w = threadIdx.x >> 6, lane = threadIdx.x & 63;
  const size_t row = (size_t)blockIdx.x * 4 + w;
  const _Float16* sr = S + row * 2048;

  f16x8 v[4];
  #pragma unroll
  for (int c = 0; c < 4; ++c)
    v[c] = *(const f16x8*)(sr + c * 512 + lane * 8);

  float m = -1e30f;
  #pragma unroll
  for (int c = 0; c < 4; ++c)
    #pragma unroll
    for (int j = 0; j < 8; ++j) m = fmaxf(m, (float)v[c][j]);
  #pragma unroll
  for (int o = 32; o >= 1; o >>= 1) m = fmaxf(m, __shfl_xor(m, o));

  float e[4][8];
  float s = 0.f;
  #pragma unroll
  for (int c = 0; c < 4; ++c)
    #pragma unroll
    for (int j = 0; j < 8; ++j) {
      e[c][j] = __expf((float)v[c][j] - m);
      s += e[c][j];
    }
  #pragma unroll
  for (int o = 32; o >= 1; o >>= 1) s += __shfl_xor(s, o);

  const float inv = 1.0f / s;
  _Float16* pr = P + row * 2048;
  #pragma unroll
  for (int c = 0; c < 4; ++c) {
    f16x8 p;
    #pragma unroll
    for (int j = 0; j < 8; ++j) p[j] = (_Float16)(e[c][j] * inv);
    *(f16x8*)(pr + c * 512 + lane * 8) = p;
  }
}

// ---------------------------------------------------------------------------
extern "C" void kernel_launch(void* const* d_in, const int* in_sizes, int n_in,
                              void* d_out, int out_size, void* d_ws, size_t ws_size,
                              hipStream_t stream)
{
  const float* Xk = (const float*)d_in[0];
  const float* Xv = (const float*)d_in[1];
  const float* Xq = (const float*)d_in[2];
  const float* WK = (const float*)d_in[3];
  const float* WV = (const float*)d_in[4];
  const float* WQ = (const float*)d_in[5];
  float* out = (float*)d_out;
  char* ws = (char*)d_ws;

  _Float16* XF   = (_Float16*)(ws);               // 0..48 MiB
  _Float16* WT   = (_Float16*)(ws + 48 * MiB);    // 48..54
  _Float16* PROJ = (_Float16*)(ws + 54 * MiB);    // 54..102 (K,V,Q)
  _Float16* VT   = (_Float16*)(ws + 102 * MiB);   // 102..118
  _Float16* SC   = (_Float16*)(ws + 118 * MiB);   // 118..150 (f16 scores)
  _Float16* P    = (_Float16*)(ws);               // alias XF (dead post-proj)

  _Float16* Kp = PROJ;
  _Float16* Vp = PROJ + MK;
  _Float16* Qp = PROJ + 2 * MK;

  auto* fP  = gemmO<1>;
  auto* fSC = gemmO<2>;
  auto* fPV = gemmO<0>;
  (void)hipFuncSetAttribute((const void*)fP,  hipFuncAttributeMaxDynamicSharedMemorySize, 73728);
  (void)hipFuncSetAttribute((const void*)fSC, hipFuncAttributeMaxDynamicSharedMemorySize, 73728);
  (void)hipFuncSetAttribute((const void*)fPV, hipFuncAttributeMaxDynamicSharedMemorySize, 73728);

  // 1) X -> f16 (k,v,q)
  convert_x<<<dim3(8192, 1, 3), 256, 0, stream>>>(Xk, Xv, Xq, XF);
  // 2) W -> W^T f16 (K,V,Q)
  transpose_conv_w<<<dim3(32, 32, 3), 256, 0, stream>>>(WK, WV, WQ, WT);
  // 3) projections: PROJ[z] = XF[z] @ WT[z]^T  (M=8192,N=1024,K=1024)
  //    768 blocks @ 2 blocks/CU
  gemmO<1><<<dim3(8, 32, 3), 512, 73728, stream>>>(
      XF, MK, WT, WSZ, PROJ, MK, 1024, 1024, 1.0f);
  // 4) V^T per batch
  transpose_v<<<dim3(32, 64, 4), 256, 0, stream>>>(Vp, VT);
  // 5) scores[b] = Q[b]@K[b]^T / sqrt(2048) -> f16  (512 blocks)
  gemmO<2><<<dim3(16, 8, 4), 512, 73728, stream>>>(
      Qp, (size_t)2048 * 1024, Kp, (size_t)2048 * 1024,
      SC, (size_t)2048 * 2048, 2048, 1024, 0.022097086912079608f);
  // 6) softmax (wave-per-row) -> P f16
  softmax_rows<<<dim3(2048), 256, 0, stream>>>(SC, P);
  // 7) out[b] = P[b] @ VT[b]^T  (M=2048,N=1024,K=2048; 256 blocks)
  gemmO<0><<<dim3(8, 8, 4), 512, 73728, stream>>>(
      P, (size_t)2048 * 2048, VT, (size_t)1024 * 2048,
      out, (size_t)2048 * 1024, 1024, 2048, 1.0f);
}

// Round 12
// 199.786 us; speedup vs baseline: 1.0418x; 1.0418x over previous
//
#include <hip/hip_runtime.h>
#include <hip/hip_bf16.h>

// ---------------------------------------------------------------------------
// AttentionHead B=4,S=2048,D=1024 — all-f16 pipeline, round 12.
// gemmO (r11 + swizzle FIX): 256x128, BK=32, 3-deep pipeline, 72 KiB LDS ->
//   2 blocks/CU. R11 bug: chunk ^= (fr&3) gave only 2 slots for the 8 lanes
//   sharing a bank-half -> 4-way conflict (6.29M). Correct (r3-r6 proven):
//   chunk ^= (row>>1)&3  -> 4 slots, 2 lanes/slot = free.
// softmax/converts/transposes unchanged.
// ws (MiB): XF@0(48) WT@48(6) PROJ@54(48) VT@102(16) SC@118(32,f16)
//           P@0(32,f16, alias XF). high-water 150 MiB.
// ---------------------------------------------------------------------------

typedef __attribute__((ext_vector_type(4))) float    f32x4;
typedef __attribute__((ext_vector_type(8))) _Float16 f16x8;
typedef __attribute__((ext_vector_type(4))) _Float16 f16x4;

constexpr size_t MiB = 1u << 20;
constexpr size_t MK  = (size_t)8192 * 1024;
constexpr size_t WSZ = (size_t)1024 * 1024;

__device__ __forceinline__ void gload_lds16(const void* g, void* l) {
  __builtin_amdgcn_global_load_lds(
      (const __attribute__((address_space(1))) unsigned int*)g,
      (__attribute__((address_space(3))) unsigned int*)l, 16, 0, 0);
}

#define MFMA16(a, b, c) __builtin_amdgcn_mfma_f32_16x16x32_f16(a, b, c, 0, 0, 0)

// XCD-chunked bijective block swizzle (requires total blocks % 8 == 0).
__device__ __forceinline__ void swz_block(int& bx, int& by, int& bz) {
  unsigned gx = gridDim.x, gy = gridDim.y;
  unsigned flat = blockIdx.x + gx * (blockIdx.y + gy * blockIdx.z);
  unsigned total = gx * gy * gridDim.z;
  unsigned cpx = total >> 3;
  unsigned s = (flat & 7) * cpx + (flat >> 3);
  bx = s % gx; s /= gx; by = s % gy; bz = s / gy;
}

// ---------------------------------------------------------------------------
__global__ __launch_bounds__(256) void convert_x(
    const float* __restrict__ x0, const float* __restrict__ x1,
    const float* __restrict__ x2, _Float16* __restrict__ XF)
{
  const int z = blockIdx.z;
  const float* x = z == 0 ? x0 : (z == 1 ? x1 : x2);
  size_t i = ((size_t)blockIdx.x * 256 + threadIdx.x) * 4;
  float4 v = *(const float4*)(x + i);
  f16x4 h = {(_Float16)v.x, (_Float16)v.y, (_Float16)v.z, (_Float16)v.w};
  *(f16x4*)(XF + (size_t)z * MK + i) = h;
}

// ---------------------------------------------------------------------------
__global__ __launch_bounds__(256) void transpose_conv_w(
    const float* __restrict__ w0, const float* __restrict__ w1,
    const float* __restrict__ w2, _Float16* __restrict__ WT)
{
  const int z = blockIdx.z;
  const float* W = z == 0 ? w0 : (z == 1 ? w1 : w2);
  _Float16* o = WT + (size_t)z * WSZ;
  __shared__ float tile[32][33];
  const int bx = blockIdx.x * 32;
  const int by = blockIdx.y * 32;
  const int tx = threadIdx.x & 31, ty = threadIdx.x >> 5;
  #pragma unroll
  for (int r = 0; r < 32; r += 8)
    tile[ty + r][tx] = W[(size_t)(by + ty + r) * 1024 + bx + tx];
  __syncthreads();
  #pragma unroll
  for (int r = 0; r < 32; r += 8)
    o[(size_t)(bx + ty + r) * 1024 + by + tx] = (_Float16)tile[tx][ty + r];
}

// ---------------------------------------------------------------------------
__global__ __launch_bounds__(256) void transpose_v(
    const _Float16* __restrict__ V, _Float16* __restrict__ Vt)
{
  const _Float16* v = V + (size_t)blockIdx.z * 2048 * 1024;
  _Float16* o = Vt + (size_t)blockIdx.z * 1024 * 2048;
  __shared__ _Float16 tile[32][33];
  const int bx = blockIdx.x * 32;   // e
  const int by = blockIdx.y * 32;   // s
  const int tx = threadIdx.x & 31, ty = threadIdx.x >> 5;
  #pragma unroll
  for (int r = 0; r < 32; r += 8)
    tile[ty + r][tx] = v[(size_t)(by + ty + r) * 1024 + bx + tx];
  __syncthreads();
  #pragma unroll
  for (int r = 0; r < 32; r += 8)
    o[(size_t)(bx + ty + r) * 2048 + by + tx] = tile[tx][ty + r];
}

// ---------------------------------------------------------------------------
// gemmO: 256(M)x128(N), BK=32, 512 thr = 8 waves (4M x 2N, wave 64x64).
// 3-deep pipeline, 3 x 24 KiB LDS buffers (A 16K @0, B 8K @16384 per buf)
// -> 72 KiB total -> 2 blocks/CU co-resident.
// Stage tile t+2 during t (3 gloads); boundary vmcnt(3) steady, 0 tail.
// Swizzle (64B rows, 4 chunks): phys_chunk = logical ^ ((row>>1)&3)
// [r3-r6 proven conflict-free: 8 lanes/bank-half spread over 4 chunks,
//  2 lanes/chunk = free per m136], applied source-side + read-side.
// MODE 0: f32*scale ; 1: f16 ; 2: f16*scale.
template <int MODE>
__global__ __launch_bounds__(512, 4) void gemmO(
    const _Float16* __restrict__ At, size_t sA,
    const _Float16* __restrict__ Bt, size_t sB,
    void* __restrict__ Cv, size_t sCz,
    int N, int K, float scale)
{
  extern __shared__ char lds[];
  int bx, by, bz;
  swz_block(bx, by, bz);
  const _Float16* A = At + (size_t)bz * sA;
  const _Float16* B = Bt + (size_t)bz * sB;

  const int gm0 = by * 256, gn0 = bx * 128;
  const int tid = threadIdx.x;
  const int lane = tid & 63, wave = tid >> 6;
  const int wm = (wave >> 1) * 64;    // 4 M groups of 64
  const int wn = (wave & 1) * 64;     // 2 N groups of 64
  const int fr = lane & 15, fq = lane >> 4;
  const int nkt = K >> 5;

  // staging: thread t -> LDS row t>>2, phys chunk t&3
  // -> global logical chunk = (t&3) ^ ((row>>1)&3) = (t&3) ^ ((t>>3)&3)
  const int clog = ((tid & 3) ^ ((tid >> 3) & 3)) * 8;   // element offset
  const _Float16* srcA = A + (size_t)(gm0 + (tid >> 2)) * K + clog;
  const _Float16* srcB = B + (size_t)(gn0 + (tid >> 2)) * K + clog;
  char* const dst0 = lds + tid * 16;

  auto STG = [&](int tile) {
    const int off = tile * 32;
    char* d = dst0 + (tile % 3) * 24576;
    gload_lds16(srcA + off,                   d);
    gload_lds16(srcA + off + (size_t)128 * K, d + 8192);
    gload_lds16(srcB + off,                   d + 16384);
  };

  // fragment reads (swizzled): row stride 64B; pc = (fq ^ ((fr>>1)&3))*16
  const int pc  = (fq ^ ((fr >> 1) & 3)) * 16;
  const int arb = (wm + fr) * 64 + pc;
  const int brb = 16384 + (wn + fr) * 64 + pc;

  f32x4 acc[4][4] = {};
  f16x8 af[4], bfr[4];

  // prologue: stage tiles 0,1 (6 loads); wait tile 0 (vmcnt 3)
  STG(0);
  if (nkt > 1) {
    STG(1);
    asm volatile("s_waitcnt vmcnt(3)" ::: "memory");
  } else {
    asm volatile("s_waitcnt vmcnt(0)" ::: "memory");
  }
  __builtin_amdgcn_s_barrier();
  __builtin_amdgcn_sched_barrier(0);

  for (int t = 0; t < nkt; ++t) {
    const char* buf = lds + (t % 3) * 24576;
    const bool st2 = (t + 2) < nkt;

    if (st2) STG(t + 2);   // buffer (t+2)%3 freed by iter t-1's barrier

    #pragma unroll
    for (int mi = 0; mi < 4; ++mi)
      af[mi] = *(const f16x8*)(buf + arb + mi * 1024);
    #pragma unroll
    for (int ni = 0; ni < 4; ++ni)
      bfr[ni] = *(const f16x8*)(buf + brb + ni * 1024);

    __builtin_amdgcn_s_setprio(1);
    #pragma unroll
    for (int mi = 0; mi < 4; ++mi)
      #pragma unroll
      for (int ni = 0; ni < 4; ++ni)
        acc[mi][ni] = MFMA16(af[mi], bfr[ni], acc[mi][ni]);
    __builtin_amdgcn_s_setprio(0);

    // boundary: tile t+1 must have landed; t+2's 3 loads may stay in flight
    if (st2)               asm volatile("s_waitcnt vmcnt(3)" ::: "memory");
    else if (t + 1 < nkt)  asm volatile("s_waitcnt vmcnt(0)" ::: "memory");
    __builtin_amdgcn_s_barrier();
    __builtin_amdgcn_sched_barrier(0);
  }

  // epilogue: C/D layout col=fr, row=fq*4+r
  const int erow = gm0 + wm + fq * 4;
  const int ecol = gn0 + wn + fr;
  #pragma unroll
  for (int m = 0; m < 4; ++m)
    #pragma unroll
    for (int n = 0; n < 4; ++n) {
      size_t base = (size_t)(erow + m * 16) * N + (ecol + n * 16);
      #pragma unroll
      for (int r = 0; r < 4; ++r) {
        float v = acc[m][n][r];
        if constexpr (MODE == 0)
          ((float*)Cv + (size_t)bz * sCz)[base + (size_t)r * N] = v * scale;
        else if constexpr (MODE == 1)
          ((_Float16*)Cv + (size_t)bz * sCz)[base + (size_t)r * N] = (_Float16)v;
        else
          ((_Float16*)Cv + (size_t)bz * sCz)[base + (size_t)r * N] =
              (_Float16)(v * scale);
      }
    }
}

// ---------------------------------------------------------------------------
// Wave-per-row softmax: scores [8192 rows][2048] f16 -> P f16. 4 rows/block.
__global__ __launch_bounds__(256) void softmax_rows(
    const _Float16* __restrict__ S, _Float16* __restrict__ P)
{
  const int w = threadIdx.x >> 6, lane = threadIdx.x & 63;
  const size_t row = (size_t)blockIdx.x * 4 + w;
  const _Float16* sr = S + row * 2048;

  f16x8 v[4];
  #pragma unroll
  for (int c = 0; c < 4; ++c)
    v[c] = *(const f16x8*)(sr + c * 512 + lane * 8);

  float m = -1e30f;
  #pragma unroll
  for (int c = 0; c < 4; ++c)
    #pragma unroll
    for (int j = 0; j < 8; ++j) m = fmaxf(m, (float)v[c][j]);
  #pragma unroll
  for (int o = 32; o >= 1; o >>= 1) m = fmaxf(m, __shfl_xor(m, o));

  float e[4][8];
  float s = 0.f;
  #pragma unroll
  for (int c = 0; c < 4; ++c)
    #pragma unroll
    for (int j = 0; j < 8; ++j) {
      e[c][j] = __expf((float)v[c][j] - m);
      s += e[c][j];
    }
  #pragma unroll
  for (int o = 32; o >= 1; o >>= 1) s += __shfl_xor(s, o);

  const float inv = 1.0f / s;
  _Float16* pr = P + row * 2048;
  #pragma unroll
  for (int c = 0; c < 4; ++c) {
    f16x8 p;
    #pragma unroll
    for (int j = 0; j < 8; ++j) p[j] = (_Float16)(e[c][j] * inv);
    *(f16x8*)(pr + c * 512 + lane * 8) = p;
  }
}

// ---------------------------------------------------------------------------
extern "C" void kernel_launch(void* const* d_in, const int* in_sizes, int n_in,
                              void* d_out, int out_size, void* d_ws, size_t ws_size,
                              hipStream_t stream)
{
  const float* Xk = (const float*)d_in[0];
  const float* Xv = (const float*)d_in[1];
  const float* Xq = (const float*)d_in[2];
  const float* WK = (const float*)d_in[3];
  const float* WV = (const float*)d_in[4];
  const float* WQ = (const float*)d_in[5];
  float* out = (float*)d_out;
  char* ws = (char*)d_ws;

  _Float16* XF   = (_Float16*)(ws);               // 0..48 MiB
  _Float16* WT   = (_Float16*)(ws + 48 * MiB);    // 48..54
  _Float16* PROJ = (_Float16*)(ws + 54 * MiB);    // 54..102 (K,V,Q)
  _Float16* VT   = (_Float16*)(ws + 102 * MiB);   // 102..118
  _Float16* SC   = (_Float16*)(ws + 118 * MiB);   // 118..150 (f16 scores)
  _Float16* P    = (_Float16*)(ws);               // alias XF (dead post-proj)

  _Float16* Kp = PROJ;
  _Float16* Vp = PROJ + MK;
  _Float16* Qp = PROJ + 2 * MK;

  auto* fP  = gemmO<1>;
  auto* fSC = gemmO<2>;
  auto* fPV = gemmO<0>;
  (void)hipFuncSetAttribute((const void*)fP,  hipFuncAttributeMaxDynamicSharedMemorySize, 73728);
  (void)hipFuncSetAttribute((const void*)fSC, hipFuncAttributeMaxDynamicSharedMemorySize, 73728);
  (void)hipFuncSetAttribute((const void*)fPV, hipFuncAttributeMaxDynamicSharedMemorySize, 73728);

  // 1) X -> f16 (k,v,q)
  convert_x<<<dim3(8192, 1, 3), 256, 0, stream>>>(Xk, Xv, Xq, XF);
  // 2) W -> W^T f16 (K,V,Q)
  transpose_conv_w<<<dim3(32, 32, 3), 256, 0, stream>>>(WK, WV, WQ, WT);
  // 3) projections: PROJ[z] = XF[z] @ WT[z]^T  (M=8192,N=1024,K=1024)
  //    768 blocks @ 2 blocks/CU
  gemmO<1><<<dim3(8, 32, 3), 512, 73728, stream>>>(
      XF, MK, WT, WSZ, PROJ, MK, 1024, 1024, 1.0f);
  // 4) V^T per batch
  transpose_v<<<dim3(32, 64, 4), 256, 0, stream>>>(Vp, VT);
  // 5) scores[b] = Q[b]@K[b]^T / sqrt(2048) -> f16  (512 blocks)
  gemmO<2><<<dim3(16, 8, 4), 512, 73728, stream>>>(
      Qp, (size_t)2048 * 1024, Kp, (size_t)2048 * 1024,
      SC, (size_t)2048 * 2048, 2048, 1024, 0.022097086912079608f);
  // 6) softmax (wave-per-row) -> P f16
  softmax_rows<<<dim3(2048), 256, 0, stream>>>(SC, P);
  // 7) out[b] = P[b] @ VT[b]^T  (M=2048,N=1024,K=2048; 256 blocks)
  gemmO<0><<<dim3(8, 8, 4), 512, 73728, stream>>>(
      P, (size_t)2048 * 2048, VT, (size_t)1024 * 2048,
      out, (size_t)2048 * 1024, 1024, 2048, 1.0f);
}